// Round 9
// baseline (1011.870 us; speedup 1.0000x reference)
//
#include <hip/hip_runtime.h>
#include <math.h>

constexpr int N = 50000;
constexpr int E = 800000;
constexpr int H = 64;
constexpr int NWAVE = 12500;          // node stride between a wave's 4 groups
constexpr int AGB = 3125;             // agg blocks (tiles) per graph
constexpr int SCB = 49;               // scan blocks per graph: 49*1024 >= N

// XCD-affinity swizzle constants (stateless, replay-safe).
constexpr int FULLR = AGB / 3;        // 1041 full rounds
constexpr int FULLB = FULLR * 8;      // 8328 bids in full rounds
constexpr int G2F   = FULLR * 2;      // 2082 g2 tiles from full rounds
constexpr int REM0  = AGB - 3*FULLR;  // 2 leftover g0 tiles
static_assert(3*FULLR + REM0 == AGB, "g0 cover");
static_assert(2*FULLR + (3*AGB - FULLB - 2*REM0) == AGB, "g2 cover");

typedef unsigned short ushort_t;
typedef unsigned int uint_t;
typedef unsigned char uchar_t;
typedef float fl2 __attribute__((ext_vector_type(2)));
typedef float fl4 __attribute__((ext_vector_type(4)));

// ---- workspace layout (element offsets) ----
// X region holds the per-graph fp8 h_gat table ((N+1)*64 B).
constexpr size_t X_OFF    = 0;                          // h_gat table (fp8)
constexpr size_t NO_OFF   = X_OFF + (size_t)N*H;        // N   deg_out^-1/2
constexpr size_t NI_OFF   = NO_OFF + N;                 // N   deg_in^-1/2
constexpr size_t EL_OFF   = NI_OFF + N;                 // N+1 GAT el (incl supernode)
constexpr size_t ER_OFF   = EL_OFF + (N+1);             // N   GAT er
constexpr size_t PAD_OFF  = ER_OFF + N;                 // (unused; layout kept)
constexpr size_t GF = ((PAD_OFF + E + 3*N + 255)/256)*256;

constexpr size_t RP_OFF = 0;                            // N+1 row_ptr (CSR by dst)
constexpr size_t CT_OFF = RP_OFF + (N+1);               // N   count -> scatter cursor
constexpr size_t SS_OFF = CT_OFF + N;                   // E   src sorted by dst
constexpr size_t GI = ((SS_OFF + E + 255)/256)*256;

// per-graph fp8 h_gcn block: 64 B per row; row N = supernode (unused for gcn)
constexpr size_t GH = (size_t)(N+1)*64;                 // bytes

// fp8 helpers: HW RNE pack/unpack (OCP e4m3 on gfx950)
__device__ inline uint_t f8pack4(float a, float b, float c, float d){
  int r = __builtin_amdgcn_cvt_pk_fp8_f32(a, b, 0, false);
  r = __builtin_amdgcn_cvt_pk_fp8_f32(c, d, r, true);
  return (uint_t)r;
}
__device__ inline fl4 f8up4(uint_t v){
  fl2 lo = __builtin_amdgcn_cvt_pk_f32_fp8((int)v, false);
  fl2 hi = __builtin_amdgcn_cvt_pk_f32_fp8((int)v, true);
  fl4 r; r.x = lo.x; r.y = lo.y; r.z = hi.x; r.w = hi.y;
  return r;
}

// Deterministic bid -> (graph, tile) swizzle for XCD L2 affinity.
__device__ inline void swz_tile(int bid, int& g, int& b){
  if (bid < FULLB){
    int r = bid >> 3, s = bid & 7;
    if (s < 3){ g = 0; b = r*3 + s; }
    else if (s < 6){ g = 1; b = r*3 + (s-3); }
    else { g = 2; b = r*2 + (s-6); }
  } else {
    int t = bid - FULLB;
    if (t < REM0){ g = 0; b = 3*FULLR + t; }
    else if (t < 2*REM0){ g = 1; b = 3*FULLR + (t-REM0); }
    else { g = 2; b = G2F + (t-2*REM0); }
  }
}

// ---- prep: single-pass atomic counting sort (edges read 2x total, not 16x) ----
__global__ __launch_bounds__(256) void k_zero(int* ib, int* nocnt) {
  int g = blockIdx.y;
  int i = blockIdx.x*256 + threadIdx.x;
  if (i < N){
    ib[(size_t)g*GI + CT_OFF + i] = 0;
    nocnt[(size_t)g*N + i] = 0;
  }
}

// in-degree (ct) and out-degree (nocnt) via device-scope atomics:
// 4.8M adds over 300K addresses (avg 16/addr, Poisson) - low contention.
__global__ __launch_bounds__(256) void k_count(int* ib, int* nocnt,
    const int* s0,const int* d0,const int* s1,const int* d1,const int* s2,const int* d2) {
  int g = blockIdx.y;
  const int* s = g==0?s0:(g==1?s1:s2);
  const int* d = g==0?d0:(g==1?d1:d2);
  int e = blockIdx.x*256 + threadIdx.x;
  if (e < E){
    atomicAdd(ib + (size_t)g*GI + CT_OFF + d[e], 1);
    atomicAdd(nocnt + (size_t)g*N + s[e], 1);
  }
}

// ---- hierarchical exclusive scan of ct -> rp ----
__global__ __launch_bounds__(1024) void k_scan_local(int* ib, int* pt) {
  int g = blockIdx.y;
  int* ig = ib + (size_t)g*GI;
  int i = blockIdx.x*1024 + threadIdx.x;
  int c = (i < N) ? ig[CT_OFF + i] : 0;
  __shared__ int sh[1024];
  sh[threadIdx.x] = c; __syncthreads();
  #pragma unroll
  for (int off=1; off<1024; off<<=1){
    int t = (threadIdx.x>=off) ? sh[threadIdx.x-off] : 0;
    __syncthreads();
    sh[threadIdx.x] += t;
    __syncthreads();
  }
  if (i < N) ig[RP_OFF + i] = sh[threadIdx.x] - c;       // local exclusive
  if (threadIdx.x == 1023) pt[g*SCB + blockIdx.x] = sh[1023];
}

__global__ void k_scan_part(int* pt) {
  int g = blockIdx.x;
  __shared__ int sh[SCB];
  int t = threadIdx.x;
  if (t < SCB) sh[t] = pt[g*SCB + t];
  __syncthreads();
  if (t == 0){
    int run = 0;
    for (int b=0;b<SCB;b++){ int c = sh[b]; sh[b] = run; run += c; }
  }
  __syncthreads();
  if (t < SCB) pt[g*SCB + t] = sh[t];
}

// finalize rp, norms; CT slot becomes the scatter cursor (init = rp).
__global__ __launch_bounds__(1024) void k_scan_apply(float* fb, int* ib, const int* pt,
                                                     const int* nocnt) {
  int g = blockIdx.y;
  float* fg = fb + (size_t)g*GF;
  int* ig = ib + (size_t)g*GI;
  int i = blockIdx.x*1024 + threadIdx.x;
  if (i >= N) return;
  int base = pt[g*SCB + blockIdx.x];
  int r = ig[RP_OFF + i] + base;
  ig[RP_OFF + i] = r;
  int c = ig[CT_OFF + i];
  ig[CT_OFF + i] = r;                                    // scatter cursor
  int o = nocnt[(size_t)g*N + i];
  fg[NI_OFF + i] = rsqrtf((float)(c+1));                 // +1 self loop
  fg[NO_OFF + i] = rsqrtf((float)(o+1));
  if (i == N-1) ig[RP_OFF + N] = r + c;
}

// scatter via per-node atomic cursors; pos<E guard keeps any profiler-replay
// double-advance memory-safe (within-bucket order is atomic-order, same
// non-deterministic contract as the previous LDS-cursor design).
__global__ __launch_bounds__(256) void k_scatter(int* ib,
    const int* s0,const int* d0,const int* s1,const int* d1,const int* s2,const int* d2) {
  int g = blockIdx.y;
  const int* s = g==0?s0:(g==1?s1:s2);
  const int* d = g==0?d0:(g==1?d1:d2);
  int* ig = ib + (size_t)g*GI;
  int e = blockIdx.x*256 + threadIdx.x;
  if (e < E){
    int pos = atomicAdd(ig + CT_OFF + d[e], 1);
    if (pos < E) ig[SS_OFF + pos] = s[e];
  }
}

// Initial GCN dense layer: reads INPUT x directly (x never staged to ws).
__global__ __launch_bounds__(256) void k_mm_gcn0(float* fb, uchar_t* hb,
    const float* x0,const float* x1,const float* x2,
    const float* W0,const float* W1,const float* W2, float* sm) {
  if (blockIdx.x==0 && blockIdx.y==0){
    for (int i=threadIdx.x;i<384;i+=256) sm[i]=0.f;
  }
  int g = blockIdx.y;
  const float* W = g==0?W0:(g==1?W1:W2);
  const float* x = g==0?x0:(g==1?x1:x2);
  __shared__ float Ws[64*64];
  __shared__ float Xs[64*65];
  float* fg = fb + (size_t)g*GF;
  int row0 = blockIdx.x*64;
  for (int i=threadIdx.x; i<4096; i+=256) Ws[i] = W[i];
  int r = threadIdx.x>>2, q = threadIdx.x&3;
  int row = row0 + r;
  int rowc = row < N ? row : N-1;
  {
    const float4* xr = (const float4*)(x + (size_t)rowc*64) + q*4;
    float* xd = Xs + r*65 + q*16;
    #pragma unroll
    for (int c=0;c<4;c++){ float4 v = xr[c]; xd[4*c]=v.x; xd[4*c+1]=v.y; xd[4*c+2]=v.z; xd[4*c+3]=v.w; }
  }
  __syncthreads();
  float acc[16];
  #pragma unroll
  for (int j=0;j<16;j++) acc[j]=0.f;
  const float* xrow = Xs + r*65;
  #pragma unroll 8
  for (int k=0;k<64;k++){
    float xk = xrow[k];
    const float* wr = Ws + k*64 + q*16;
    #pragma unroll
    for (int j=0;j<16;j++) acc[j] = fmaf(xk, wr[j], acc[j]);
  }
  if (row >= N) return;
  float sc = fg[NO_OFF + row];
  uint_t pk[4];
  #pragma unroll
  for (int j=0;j<4;j++)
    pk[j] = f8pack4(acc[4*j]*sc, acc[4*j+1]*sc, acc[4*j+2]*sc, acc[4*j+3]*sc);
  *(uint4*)(hb + (size_t)g*GH + (size_t)row*64 + q*16) = *(const uint4*)pk;
}

// GCN aggregate, group-per-node, FUSED with the GAT dense layer (unchanged
// from R8 except the defensive s0/s1 clamp).
__global__ __launch_bounds__(256) void k_gcn_agg(float* fb, const uchar_t* hb, const int* ib,
    const float* b0, const float* b1, const float* b2, int lay, float* sm,
    const float* Wgat, const float* al, const float* ar, int fuse) {
  int g, blk;
  swz_tile(blockIdx.x, g, blk);
  const float* b = (g==0?b0:(g==1?b1:b2)) + lay*64;
  float* fg = fb + (size_t)g*GF;
  const uint_t* hu = (const uint_t*)(hb + (size_t)g*GH);  // h_gcn (read)
  uint_t* hgat = (uint_t*)(fg + X_OFF);                   // h_gat (write)
  const int* ig = ib + (size_t)g*GI;
  int wave = threadIdx.x >> 6, lane = threadIdx.x & 63;
  int v = lane >> 4, u = lane & 15;
  int base = lane & 48;
  int w = blk*4 + wave;
  int node = w + NWAVE*v;
  const int* rp = ig + RP_OFF;
  const int* ss = ig + SS_OFF;
  fl4 bl = ((const fl4*)b)[u];
  __shared__ float Wsl[4096];
  __shared__ float xsl[16*68];          // padded stride 68: bank-spread slots
  __shared__ float ssum[4][64];
  __shared__ float smx[4][64];
  if (fuse){
    const float* Wg = Wgat + (size_t)g*4096;
    for (int i=threadIdx.x;i<4096;i+=256) Wsl[i] = Wg[i];
  }
  __syncthreads();

  int s0 = rp[node], s1 = rp[node+1];
  if (s1 > E) s1 = E;                  // defensive bound (replay corruption)
  if (s0 > s1) s0 = s1;
  float ni = fg[NI_OFF + node];
  fl4 a = f8up4(hu[(size_t)node*16 + u]);                 // self loop (pre-scaled)
  int idxv;
  { int ei = s0 + u; int ec = ei < s1 ? ei : (s0 < s1 ? s0 : 0);
    idxv = __builtin_nontemporal_load(&ss[ec]); }

  for (int kb = s0; kb < s1; kb += 16){                   // group-divergent loop
    uint_t vv[16];
    #pragma unroll
    for (int j=0;j<16;j++){
      int ij = __shfl(idxv, base + j);
      vv[j] = hu[(size_t)ij*16 + u];
    }
    int kn = kb + 16;
    if (kn < s1){                                         // prefetch next round
      int ei = kn + u; int ec = ei < s1 ? ei : s0;
      idxv = __builtin_nontemporal_load(&ss[ec]);
    }
    #pragma unroll
    for (int j=0;j<16;j++){
      float wj = (kb + j) < s1 ? 1.f : 0.f;
      fl4 f = f8up4(vv[j]);
      a.x = fmaf(wj, f.x, a.x); a.y = fmaf(wj, f.y, a.y);
      a.z = fmaf(wj, f.z, a.z); a.w = fmaf(wj, f.w, a.w);
    }
  }

  fl4 vo;
  vo.x = fmaf(a.x, ni, bl.x); vo.x = vo.x > 0.f ? vo.x : 0.f;
  vo.y = fmaf(a.y, ni, bl.y); vo.y = vo.y > 0.f ? vo.y : 0.f;
  vo.z = fmaf(a.z, ni, bl.z); vo.z = vo.z > 0.f ? vo.z : 0.f;
  vo.w = fmaf(a.w, ni, bl.w); vo.w = vo.w > 0.f ? vo.w : 0.f;

  if (fuse){
    int slot = wave*4 + v;
    *(fl4*)&xsl[slot*68 + 4*u] = vo;    // same-wave write->read: lgkm-ordered
    fl4 hacc = {0.f,0.f,0.f,0.f};
    #pragma unroll 4
    for (int k4=0;k4<16;k4++){
      fl4 xv = *(fl4*)&xsl[slot*68 + 4*k4];
      #pragma unroll
      for (int j=0;j<4;j++){
        float xk = j==0?xv.x:(j==1?xv.y:(j==2?xv.z:xv.w));
        fl4 wv = *(fl4*)&Wsl[(4*k4+j)*64 + 4*u];
        hacc.x = fmaf(xk, wv.x, hacc.x); hacc.y = fmaf(xk, wv.y, hacc.y);
        hacc.z = fmaf(xk, wv.z, hacc.z); hacc.w = fmaf(xk, wv.w, hacc.w);
      }
    }
    hgat[(size_t)node*16 + u] = f8pack4(hacc.x, hacc.y, hacc.z, hacc.w);
    fl4 a4 = *(const fl4*)&al[g*64 + 4*u];
    fl4 r4 = *(const fl4*)&ar[g*64 + 4*u];
    float elp = hacc.x*a4.x + hacc.y*a4.y + hacc.z*a4.z + hacc.w*a4.w;
    float erp = hacc.x*r4.x + hacc.y*r4.y + hacc.z*r4.z + hacc.w*r4.w;
    elp += __shfl_xor(elp,1); elp += __shfl_xor(elp,2);
    elp += __shfl_xor(elp,4); elp += __shfl_xor(elp,8);
    erp += __shfl_xor(erp,1); erp += __shfl_xor(erp,2);
    erp += __shfl_xor(erp,4); erp += __shfl_xor(erp,8);
    if (u == 0){
      fg[EL_OFF + node] = elp;
      fg[ER_OFF + node] = erp;
    }
  }

  // readout: sum/max across the wave's 4 nodes (groups) once
  fl4 vs = vo, vm = vo;
  vs.x += __shfl_xor(vs.x,16); vs.x += __shfl_xor(vs.x,32);
  vs.y += __shfl_xor(vs.y,16); vs.y += __shfl_xor(vs.y,32);
  vs.z += __shfl_xor(vs.z,16); vs.z += __shfl_xor(vs.z,32);
  vs.w += __shfl_xor(vs.w,16); vs.w += __shfl_xor(vs.w,32);
  vm.x = fmaxf(vm.x, __shfl_xor(vm.x,16)); vm.x = fmaxf(vm.x, __shfl_xor(vm.x,32));
  vm.y = fmaxf(vm.y, __shfl_xor(vm.y,16)); vm.y = fmaxf(vm.y, __shfl_xor(vm.y,32));
  vm.z = fmaxf(vm.z, __shfl_xor(vm.z,16)); vm.z = fmaxf(vm.z, __shfl_xor(vm.z,32));
  vm.w = fmaxf(vm.w, __shfl_xor(vm.w,16)); vm.w = fmaxf(vm.w, __shfl_xor(vm.w,32));
  if (lane < 16){
    ((fl4*)ssum[wave])[u] = vs;
    ((fl4*)smx[wave])[u]  = vm;
  }
  __syncthreads();
  if (threadIdx.x < 64){
    int t = threadIdx.x;
    float s = ssum[0][t]+ssum[1][t]+ssum[2][t]+ssum[3][t];
    float mx = fmaxf(fmaxf(smx[0][t],smx[1][t]), fmaxf(smx[2][t],smx[3][t]));
    atomicAdd(&sm[g*64 + t], s);
    atomicMax((int*)sm + 192 + g*64 + t, __float_as_int(mx));  // v>=0: int order == float order
  }
}

// readout finalize + cross-graph feature exchange + supernode h_gat row, el[N].
// Re-zeroes its source graph's sm slots (read-then-zero, block-exclusive).
__global__ void k_exchange(float* fb, float* sm, const float* Wx, const float* bx,
                           const float* Wgat, const float* al, int it) {
  int gt = blockIdx.x;     // target graph
  int t = threadIdx.x;     // 64 threads
  int src, widx;
  if ((it & 1) == 0){ src = (gt==0)?1:(gt==1)?2:0; widx = (gt==0)?1:(gt==1)?0:2; }
  else              { src = (gt==0)?2:(gt==1)?0:1; widx = (gt==0)?5:(gt==1)?3:4; }
  __shared__ float ro[128];
  __shared__ float f[64];
  __shared__ float red[64];
  __shared__ float hsb[64];
  ro[t]      = sm[src*64 + t] * (1.0f/(float)N);
  ro[64 + t] = __int_as_float(((int*)sm)[192 + src*64 + t]);
  sm[src*64 + t] = 0.f;                    // exclusive: only this block reads src
  ((int*)sm)[192 + src*64 + t] = 0;
  __syncthreads();
  float a = bx[widx*64 + t];
  for (int k=0;k<128;k++) a = fmaf(ro[k], Wx[(size_t)widx*8192 + k*64 + t], a);
  a = a > 0.f ? a : 0.f;
  f[t] = a;
  __syncthreads();
  float* fg = fb + (size_t)gt*GF;
  float hs = 0.f;
  for (int k=0;k<64;k++) hs = fmaf(f[k], Wgat[(size_t)gt*4096 + k*64 + t], hs);
  hsb[t] = hs;
  red[t] = hs * al[gt*64 + t];
  __syncthreads();
  if (t < 16){
    uint_t r = f8pack4(hsb[4*t], hsb[4*t+1], hsb[4*t+2], hsb[4*t+3]);
    ((uint_t*)(fg + X_OFF))[(size_t)N*16 + t] = r;       // supernode h_gat row
  }
  if (t == 0){
    float e = 0.f;
    for (int k=0;k<64;k++) e += red[k];
    fg[EL_OFF + N] = e;                      // el for supernode
  }
}

// GAT aggregation with fused online softmax AND the next GCN dense layer
// (unchanged from R8 except the defensive s0/s1 clamp).
__global__ __launch_bounds__(256) void k_gat_agg(float* fb, uchar_t* hb, const int* ib,
    const float* bgat, const float* Wc0, const float* Wc1, const float* Wc2, int lay) {
  int g, blk;
  swz_tile(blockIdx.x, g, blk);
  float* fg = fb + (size_t)g*GF;
  const uint_t* hu = (const uint_t*)(fg + X_OFF);         // h_gat (read)
  uint_t* hout = (uint_t*)(hb + (size_t)g*GH);            // h_gcn (write)
  const int* ig = ib + (size_t)g*GI;
  int wave = threadIdx.x >> 6, lane = threadIdx.x & 63;
  int v = lane >> 4, u = lane & 15;
  int base = lane & 48;
  int w = blk*4 + wave;
  int node = w + NWAVE*v;
  const int* rp = ig + RP_OFF;
  const int* ss = ig + SS_OFF;
  const float* el = fg + EL_OFF;
  fl4 bg = ((const fl4*)(bgat + g*64))[u];
  __shared__ float Wsl[4096];
  __shared__ float xsl[16*68];
  {
    const float* W = (g==0?Wc0:(g==1?Wc1:Wc2)) + (size_t)lay*4096;
    for (int i=threadIdx.x;i<4096;i+=256) Wsl[i] = W[i];
  }
  __syncthreads();
  fl4 supf = f8up4(hu[(size_t)N*16 + u]);

  int s0 = rp[node], s1 = rp[node+1];
  if (s1 > E) s1 = E;                  // defensive bound (replay corruption)
  if (s0 > s1) s0 = s1;
  float ern = fg[ER_OFF + node];
  float eln = el[node];
  float elsup = el[N];
  float es = eln + ern;   es = es >= 0.f ? es : 0.2f*es;  float ts = __expf(es);
  float eu = elsup + ern; eu = eu >= 0.f ? eu : 0.2f*eu;  float tu = __expf(eu);
  fl4 fs = f8up4(hu[(size_t)node*16 + u]);
  fl4 a;
  a.x = fmaf(tu, supf.x, ts*fs.x);
  a.y = fmaf(tu, supf.y, ts*fs.y);
  a.z = fmaf(tu, supf.z, ts*fs.z);
  a.w = fmaf(tu, supf.w, ts*fs.w);
  float esum = 0.f;

  int idxv; float elv;
  { int ei = s0 + u;
    int ec = ei < s1 ? ei : (s0 < s1 ? s0 : 0);           // always a valid slot
    idxv = __builtin_nontemporal_load(&ss[ec]); }
  elv = el[idxv];                                         // safe: idxv in [0,N)

  for (int kb = s0; kb < s1; kb += 16){                   // group-divergent loop
    float xe = elv + ern; xe = xe >= 0.f ? xe : 0.2f*xe;
    float ex = __expf(xe);
    float wv = (kb + u) < s1 ? ex : 0.f;
    esum += wv;
    uint_t vv[16];
    #pragma unroll
    for (int j=0;j<16;j++){
      int ij = __shfl(idxv, base + j);
      vv[j] = hu[(size_t)ij*16 + u];
    }
    int kn = kb + 16;
    if (kn < s1){                                         // prefetch next round
      int ei = kn + u; int ec = ei < s1 ? ei : s0;
      idxv = __builtin_nontemporal_load(&ss[ec]);
      elv = el[idxv];
    }
    #pragma unroll
    for (int j=0;j<16;j++){
      float wj = __shfl(wv, base + j);                    // already zero-masked
      fl4 f = f8up4(vv[j]);
      a.x = fmaf(wj, f.x, a.x); a.y = fmaf(wj, f.y, a.y);
      a.z = fmaf(wj, f.z, a.z); a.w = fmaf(wj, f.w, a.w);
    }
  }

  esum += __shfl_xor(esum,1); esum += __shfl_xor(esum,2);
  esum += __shfl_xor(esum,4); esum += __shfl_xor(esum,8);
  float is = 1.0f / (esum + ts + tu);

  fl4 vo;                                                 // GAT output (no relu)
  vo.x = fmaf(a.x, is, bg.x); vo.y = fmaf(a.y, is, bg.y);
  vo.z = fmaf(a.z, is, bg.z); vo.w = fmaf(a.w, is, bg.w);

  // fused next-layer GCN dense: h_gcn = fp8((vo @ Wc[lay]) * no[node])
  int slot = wave*4 + v;
  *(fl4*)&xsl[slot*68 + 4*u] = vo;
  fl4 hacc = {0.f,0.f,0.f,0.f};
  #pragma unroll 4
  for (int k4=0;k4<16;k4++){
    fl4 xv = *(fl4*)&xsl[slot*68 + 4*k4];
    #pragma unroll
    for (int j=0;j<4;j++){
      float xk = j==0?xv.x:(j==1?xv.y:(j==2?xv.z:xv.w));
      fl4 wv = *(fl4*)&Wsl[(4*k4+j)*64 + 4*u];
      hacc.x = fmaf(xk, wv.x, hacc.x); hacc.y = fmaf(xk, wv.y, hacc.y);
      hacc.z = fmaf(xk, wv.z, hacc.z); hacc.w = fmaf(xk, wv.w, hacc.w);
    }
  }
  float no = fg[NO_OFF + node];
  hout[(size_t)node*16 + u] = f8pack4(hacc.x*no, hacc.y*no, hacc.z*no, hacc.w*no);
}

__global__ __launch_bounds__(384) void k_mlp(const float* sm, const float* W1, const float* b1,
    const float* W2, const float* b2, const float* W3, const float* b3, float* out) {
  __shared__ float nf[384];
  __shared__ float y1[192];
  __shared__ float y2[96];
  __shared__ float z[2];
  int t = threadIdx.x;
  int g = t / 128, j = t % 128;
  nf[t] = (j < 64) ? sm[g*64 + j] * (1.0f/(float)N)
                   : __int_as_float(((const int*)sm)[192 + g*64 + (j-64)]);
  __syncthreads();
  if (t < 192){
    float a = b1[t];
    for (int k=0;k<384;k++) a = fmaf(nf[k], W1[(size_t)k*192 + t], a);
    y1[t] = a > 0.f ? a : 0.f;
  }
  __syncthreads();
  if (t < 96){
    float a = b2[t];
    for (int k=0;k<192;k++) a = fmaf(y1[k], W2[(size_t)k*96 + t], a);
    y2[t] = a > 0.f ? a : 0.f;
  }
  __syncthreads();
  if (t < 2){
    float a = b3[t];
    for (int k=0;k<96;k++) a = fmaf(y2[k], W3[k*2 + t], a);
    z[t] = a;
  }
  __syncthreads();
  if (t == 0){
    float m = fmaxf(z[0], z[1]);
    float l = m + logf(__expf(z[0]-m) + __expf(z[1]-m));
    out[0] = z[0] - l;
    out[1] = z[1] - l;
  }
}

extern "C" void kernel_launch(void* const* d_in, const int* in_sizes, int n_in,
                              void* d_out, int out_size, void* d_ws, size_t ws_size,
                              hipStream_t stream) {
  const float* x_s  = (const float*)d_in[0];
  const float* x_g  = (const float*)d_in[1];
  const float* x_t  = (const float*)d_in[2];
  const float* Wc_s = (const float*)d_in[3];
  const float* bc_s = (const float*)d_in[4];
  const float* Wc_g = (const float*)d_in[5];
  const float* bc_g = (const float*)d_in[6];
  const float* Wc_t = (const float*)d_in[7];
  const float* bc_t = (const float*)d_in[8];
  const float* Wx   = (const float*)d_in[9];
  const float* bx   = (const float*)d_in[10];
  const float* Wgat = (const float*)d_in[11];
  const float* al   = (const float*)d_in[12];
  const float* ar   = (const float*)d_in[13];
  const float* bgat = (const float*)d_in[14];
  const float* W1   = (const float*)d_in[15];
  const float* b1   = (const float*)d_in[16];
  const float* W2   = (const float*)d_in[17];
  const float* b2   = (const float*)d_in[18];
  const float* W3   = (const float*)d_in[19];
  const float* b3   = (const float*)d_in[20];
  const int* src_s  = (const int*)d_in[21];
  const int* dst_s  = (const int*)d_in[22];
  const int* src_g  = (const int*)d_in[23];
  const int* dst_g  = (const int*)d_in[24];
  const int* src_t  = (const int*)d_in[25];
  const int* dst_t  = (const int*)d_in[26];

  float* fb = (float*)d_ws;
  int*   ib = (int*)(fb + 3*GF);
  uchar_t* hb = (uchar_t*)(ib + 3*GI);
  float* sm = (float*)(hb + 3*GH);
  int*   pt = (int*)(sm + 384);              // 3*SCB scan partials
  int*   nocnt = pt + 3*SCB + 64;            // 3*N out-degree counts
  float* out = (float*)d_out;

  dim3 b256(256);
  int mmb = (N+63)/64;
  int eb  = (E+255)/256;
  int nb  = (N+255)/256;

  // graph prep: single-pass atomic counting sort
  k_zero      <<<dim3(nb, 3),  b256, 0, stream>>>(ib, nocnt);
  k_count     <<<dim3(eb, 3),  b256, 0, stream>>>(ib, nocnt, src_s,dst_s, src_g,dst_g, src_t,dst_t);
  k_scan_local<<<dim3(SCB, 3), dim3(1024), 0, stream>>>(ib, pt);
  k_scan_part <<<dim3(3),      dim3(64),   0, stream>>>(pt);
  k_scan_apply<<<dim3(SCB, 3), dim3(1024), 0, stream>>>(fb, ib, pt, nocnt);
  k_scatter   <<<dim3(eb, 3),  b256, 0, stream>>>(ib, src_s,dst_s, src_g,dst_g, src_t,dst_t);

  // initial GCN dense from input x (x never materialized in ws)
  k_mm_gcn0 <<<dim3(mmb, 3), b256, 0, stream>>>(fb, hb, x_s, x_g, x_t,
                                                Wc_s, Wc_g, Wc_t, sm);

  for (int it = 0; it < 2; ++it) {
    k_gcn_agg <<<dim3(3*AGB), b256, 0, stream>>>(fb, hb, ib, bc_s, bc_g, bc_t, it, sm,
                                                 Wgat, al, ar, 1);
    k_exchange<<<dim3(3), dim3(64), 0, stream>>>(fb, sm, Wx, bx, Wgat, al, it);
    k_gat_agg <<<dim3(3*AGB), b256, 0, stream>>>(fb, hb, ib, bgat,
                                                 Wc_s, Wc_g, Wc_t, it+1);
  }

  // final layer readout (no fusion) + MLP head
  k_gcn_agg <<<dim3(3*AGB), b256, 0, stream>>>(fb, hb, ib, bc_s, bc_g, bc_t, 2, sm,
                                               Wgat, al, ar, 0);
  k_mlp     <<<1, 384, 0, stream>>>(sm, W1, b1, W2, b2, W3, b3, out);
}

// Round 10
// 726.660 us; speedup vs baseline: 1.3925x; 1.3925x over previous
//
#include <hip/hip_runtime.h>
#include <math.h>

constexpr int N = 50000;
constexpr int E = 800000;
constexpr int H = 64;
constexpr int NWAVE = 12500;          // node stride between a wave's 4 groups
constexpr int AGB = 3125;             // agg blocks (tiles) per graph
constexpr int SCB = 49;               // scan blocks per graph: 49*1024 >= N
constexpr int RNG = 8;                // histogram ranges per graph
constexpr int BPR = 8;                // edge slices per graph
constexpr int BINS = N / RNG;         // 6250 bins per range
constexpr int ES   = E / BPR;         // 100000 edges per slice

// XCD-affinity swizzle constants (stateless, replay-safe).
constexpr int FULLR = AGB / 3;        // 1041 full rounds
constexpr int FULLB = FULLR * 8;      // 8328 bids in full rounds
constexpr int G2F   = FULLR * 2;      // 2082 g2 tiles from full rounds
constexpr int REM0  = AGB - 3*FULLR;  // 2 leftover g0 tiles
static_assert(3*FULLR + REM0 == AGB, "g0 cover");
static_assert(2*FULLR + (3*AGB - FULLB - 2*REM0) == AGB, "g2 cover");

typedef unsigned short ushort_t;
typedef unsigned int uint_t;
typedef unsigned char uchar_t;
typedef float fl2 __attribute__((ext_vector_type(2)));
typedef float fl4 __attribute__((ext_vector_type(4)));

// ---- workspace layout (element offsets) ----
// X region holds the per-graph fp8 h_gat table ((N+1)*64 B).
constexpr size_t X_OFF    = 0;                          // h_gat table (fp8)
constexpr size_t NO_OFF   = X_OFF + (size_t)N*H;        // N   deg_out^-1/2
constexpr size_t NI_OFF   = NO_OFF + N;                 // N   deg_in^-1/2
constexpr size_t EL_OFF   = NI_OFF + N;                 // N+1 GAT el (incl supernode)
constexpr size_t ER_OFF   = EL_OFF + (N+1);             // N   GAT er
constexpr size_t PAD_OFF  = ER_OFF + N;                 // slack (layout kept)
constexpr size_t GF = ((PAD_OFF + E + 3*N + 255)/256)*256;

constexpr size_t RP_OFF = 0;                            // N+1 row_ptr (CSR by dst)
constexpr size_t CT_OFF = RP_OFF + (N+1);               // N   in-degree count
constexpr size_t SS_OFF = CT_OFF + N;                   // E   src sorted by dst
constexpr size_t GI = ((SS_OFF + E + 255)/256)*256;

// per-graph fp8 h_gcn block: 64 B per row; row N = supernode (unused for gcn)
constexpr size_t GH = (size_t)(N+1)*64;                 // bytes

// fp8 helpers: HW RNE pack/unpack (OCP e4m3 on gfx950)
__device__ inline uint_t f8pack4(float a, float b, float c, float d){
  int r = __builtin_amdgcn_cvt_pk_fp8_f32(a, b, 0, false);
  r = __builtin_amdgcn_cvt_pk_fp8_f32(c, d, r, true);
  return (uint_t)r;
}
__device__ inline fl4 f8up4(uint_t v){
  fl2 lo = __builtin_amdgcn_cvt_pk_f32_fp8((int)v, false);
  fl2 hi = __builtin_amdgcn_cvt_pk_f32_fp8((int)v, true);
  fl4 r; r.x = lo.x; r.y = lo.y; r.z = hi.x; r.w = hi.y;
  return r;
}

// Deterministic bid -> (graph, tile) swizzle for XCD L2 affinity.
__device__ inline void swz_tile(int bid, int& g, int& b){
  if (bid < FULLB){
    int r = bid >> 3, s = bid & 7;
    if (s < 3){ g = 0; b = r*3 + s; }
    else if (s < 6){ g = 1; b = r*3 + (s-3); }
    else { g = 2; b = r*2 + (s-6); }
  } else {
    int t = bid - FULLB;
    if (t < REM0){ g = 0; b = 3*FULLR + t; }
    else if (t < 2*REM0){ g = 1; b = 3*FULLR + (t-REM0); }
    else { g = 2; b = G2F + (t-2*REM0); }
  }
}

// ---- prep: range-partitioned LDS histograms (PROVEN design, reverted from
// the R9 atomic scatter: coalesced re-reads are ~free, scattered 4B global
// stores cost 16x write amplification + cross-XCD line ping-pong) ----
__global__ __launch_bounds__(1024) void k_hist(int* parts_ct, int* parts_no,
    const int* s0,const int* d0,const int* s1,const int* d1,const int* s2,const int* d2) {
  int sl = blockIdx.x, r = blockIdx.y, g = blockIdx.z;
  const int* s = g==0?s0:(g==1?s1:s2);
  const int* d = g==0?d0:(g==1?d1:d2);
  __shared__ int hc[BINS];
  __shared__ int hn[BINS];
  for (int i=threadIdx.x;i<BINS;i+=1024){ hc[i]=0; hn[i]=0; }
  __syncthreads();
  int lo = r*BINS, hi = lo+BINS;
  int e0 = sl*ES, e1 = e0+ES;
  for (int e=e0+threadIdx.x; e<e1; e+=1024){
    int ds = d[e], sr = s[e];
    if (ds>=lo && ds<hi) atomicAdd(&hc[ds-lo],1);
    if (sr>=lo && sr<hi) atomicAdd(&hn[sr-lo],1);
  }
  __syncthreads();
  size_t base = ((size_t)g*BPR + sl)*N + lo;
  for (int i=threadIdx.x;i<BINS;i+=1024){
    parts_ct[base+i]=hc[i];
    parts_no[base+i]=hn[i];
  }
}

// ---- hierarchical exclusive scan of cnt -> rp (all parallel) ----
__global__ __launch_bounds__(1024) void k_scan_local(int* ib, int* pt, const int* parts_ct) {
  int g = blockIdx.y;
  int* ig = ib + (size_t)g*GI;
  int i = blockIdx.x*1024 + threadIdx.x;
  int c = 0;
  if (i < N){
    #pragma unroll
    for (int s=0;s<BPR;s++) c += parts_ct[((size_t)g*BPR+s)*N + i];
    ig[CT_OFF + i] = c;
  }
  __shared__ int sh[1024];
  sh[threadIdx.x] = c; __syncthreads();
  #pragma unroll
  for (int off=1; off<1024; off<<=1){
    int t = (threadIdx.x>=off) ? sh[threadIdx.x-off] : 0;
    __syncthreads();
    sh[threadIdx.x] += t;
    __syncthreads();
  }
  if (i < N) ig[RP_OFF + i] = sh[threadIdx.x] - c;       // local exclusive
  if (threadIdx.x == 1023) pt[g*SCB + blockIdx.x] = sh[1023];
}

__global__ void k_scan_part(int* pt) {
  int g = blockIdx.x;
  __shared__ int sh[SCB];
  int t = threadIdx.x;
  if (t < SCB) sh[t] = pt[g*SCB + t];
  __syncthreads();
  if (t == 0){
    int run = 0;
    for (int b=0;b<SCB;b++){ int c = sh[b]; sh[b] = run; run += c; }
  }
  __syncthreads();
  if (t < SCB) pt[g*SCB + t] = sh[t];
}

__global__ __launch_bounds__(1024) void k_scan_apply(float* fb, int* ib, const int* pt,
                                                     const int* parts_no) {
  int g = blockIdx.y;
  float* fg = fb + (size_t)g*GF;
  int* ig = ib + (size_t)g*GI;
  int i = blockIdx.x*1024 + threadIdx.x;
  if (i >= N) return;
  int base = pt[g*SCB + blockIdx.x];
  int r = ig[RP_OFF + i] + base;
  ig[RP_OFF + i] = r;
  int c = ig[CT_OFF + i];
  int o = 0;
  #pragma unroll
  for (int s=0;s<BPR;s++) o += parts_no[((size_t)g*BPR+s)*N + i];
  fg[NI_OFF + i] = rsqrtf((float)(c+1));                 // +1 self loop
  fg[NO_OFF + i] = rsqrtf((float)(o+1));
  if (i == N-1) ig[RP_OFF + N] = r + c;
}

// per-(slice,bin) exclusive prefix over slices -> exact scatter offsets
__global__ __launch_bounds__(256) void k_slice_off(const int* ib, const int* parts_ct, int* off) {
  int g = blockIdx.y;
  int i = blockIdx.x*256 + threadIdx.x;
  if (i >= N) return;
  int base = ib[(size_t)g*GI + RP_OFF + i];
  #pragma unroll
  for (int s=0;s<BPR;s++){
    size_t idx = ((size_t)g*BPR+s)*N + i;
    off[idx] = base;
    base += parts_ct[idx];
  }
}

// scatter: LDS cursors per range; writes confined to an L2-resident window
// per (slice,range) block and written exactly once (no global atomics).
__global__ __launch_bounds__(1024) void k_scatter_r(int* ib, const int* off,
    const int* s0,const int* d0,const int* s1,const int* d1,const int* s2,const int* d2) {
  int sl = blockIdx.x, r = blockIdx.y, g = blockIdx.z;
  const int* s = g==0?s0:(g==1?s1:s2);
  const int* d = g==0?d0:(g==1?d1:d2);
  int* ss = ib + (size_t)g*GI + SS_OFF;
  __shared__ int cur[BINS];
  int lo = r*BINS;
  size_t ob = ((size_t)g*BPR + sl)*N + lo;
  for (int i=threadIdx.x;i<BINS;i+=1024) cur[i] = off[ob+i];
  __syncthreads();
  int e0 = sl*ES, e1 = e0+ES;
  for (int e=e0+threadIdx.x; e<e1; e+=1024){
    int ds = d[e];
    if (ds>=lo && ds<lo+BINS){
      int pos = atomicAdd(&cur[ds-lo],1);
      ss[pos] = s[e];
    }
  }
}

// Initial GCN dense layer: reads INPUT x directly (x never staged to ws).
__global__ __launch_bounds__(256) void k_mm_gcn0(float* fb, uchar_t* hb,
    const float* x0,const float* x1,const float* x2,
    const float* W0,const float* W1,const float* W2, float* sm) {
  if (blockIdx.x==0 && blockIdx.y==0){
    for (int i=threadIdx.x;i<384;i+=256) sm[i]=0.f;
  }
  int g = blockIdx.y;
  const float* W = g==0?W0:(g==1?W1:W2);
  const float* x = g==0?x0:(g==1?x1:x2);
  __shared__ float Ws[64*64];
  __shared__ float Xs[64*65];
  float* fg = fb + (size_t)g*GF;
  int row0 = blockIdx.x*64;
  for (int i=threadIdx.x; i<4096; i+=256) Ws[i] = W[i];
  int r = threadIdx.x>>2, q = threadIdx.x&3;
  int row = row0 + r;
  int rowc = row < N ? row : N-1;
  {
    const float4* xr = (const float4*)(x + (size_t)rowc*64) + q*4;
    float* xd = Xs + r*65 + q*16;
    #pragma unroll
    for (int c=0;c<4;c++){ float4 v = xr[c]; xd[4*c]=v.x; xd[4*c+1]=v.y; xd[4*c+2]=v.z; xd[4*c+3]=v.w; }
  }
  __syncthreads();
  float acc[16];
  #pragma unroll
  for (int j=0;j<16;j++) acc[j]=0.f;
  const float* xrow = Xs + r*65;
  #pragma unroll 8
  for (int k=0;k<64;k++){
    float xk = xrow[k];
    const float* wr = Ws + k*64 + q*16;
    #pragma unroll
    for (int j=0;j<16;j++) acc[j] = fmaf(xk, wr[j], acc[j]);
  }
  if (row >= N) return;
  float sc = fg[NO_OFF + row];
  uint_t pk[4];
  #pragma unroll
  for (int j=0;j<4;j++)
    pk[j] = f8pack4(acc[4*j]*sc, acc[4*j+1]*sc, acc[4*j+2]*sc, acc[4*j+3]*sc);
  *(uint4*)(hb + (size_t)g*GH + (size_t)row*64 + q*16) = *(const uint4*)pk;
}

// GCN aggregate, group-per-node, FUSED with the GAT dense layer.
__global__ __launch_bounds__(256) void k_gcn_agg(float* fb, const uchar_t* hb, const int* ib,
    const float* b0, const float* b1, const float* b2, int lay, float* sm,
    const float* Wgat, const float* al, const float* ar, int fuse) {
  int g, blk;
  swz_tile(blockIdx.x, g, blk);
  const float* b = (g==0?b0:(g==1?b1:b2)) + lay*64;
  float* fg = fb + (size_t)g*GF;
  const uint_t* hu = (const uint_t*)(hb + (size_t)g*GH);  // h_gcn (read)
  uint_t* hgat = (uint_t*)(fg + X_OFF);                   // h_gat (write)
  const int* ig = ib + (size_t)g*GI;
  int wave = threadIdx.x >> 6, lane = threadIdx.x & 63;
  int v = lane >> 4, u = lane & 15;
  int base = lane & 48;
  int w = blk*4 + wave;
  int node = w + NWAVE*v;
  const int* rp = ig + RP_OFF;
  const int* ss = ig + SS_OFF;
  fl4 bl = ((const fl4*)b)[u];
  __shared__ float Wsl[4096];
  __shared__ float xsl[16*68];          // padded stride 68: bank-spread slots
  __shared__ float ssum[4][64];
  __shared__ float smx[4][64];
  if (fuse){
    const float* Wg = Wgat + (size_t)g*4096;
    for (int i=threadIdx.x;i<4096;i+=256) Wsl[i] = Wg[i];
  }
  __syncthreads();

  int s0 = rp[node], s1 = rp[node+1];
  if (s1 > E) s1 = E;                  // defensive bound
  if (s0 > s1) s0 = s1;
  float ni = fg[NI_OFF + node];
  fl4 a = f8up4(hu[(size_t)node*16 + u]);                 // self loop (pre-scaled)
  int idxv;
  { int ei = s0 + u; int ec = ei < s1 ? ei : (s0 < s1 ? s0 : 0);
    idxv = __builtin_nontemporal_load(&ss[ec]); }

  for (int kb = s0; kb < s1; kb += 16){                   // group-divergent loop
    uint_t vv[16];
    #pragma unroll
    for (int j=0;j<16;j++){
      int ij = __shfl(idxv, base + j);
      vv[j] = hu[(size_t)ij*16 + u];
    }
    int kn = kb + 16;
    if (kn < s1){                                         // prefetch next round
      int ei = kn + u; int ec = ei < s1 ? ei : s0;
      idxv = __builtin_nontemporal_load(&ss[ec]);
    }
    #pragma unroll
    for (int j=0;j<16;j++){
      float wj = (kb + j) < s1 ? 1.f : 0.f;
      fl4 f = f8up4(vv[j]);
      a.x = fmaf(wj, f.x, a.x); a.y = fmaf(wj, f.y, a.y);
      a.z = fmaf(wj, f.z, a.z); a.w = fmaf(wj, f.w, a.w);
    }
  }

  fl4 vo;
  vo.x = fmaf(a.x, ni, bl.x); vo.x = vo.x > 0.f ? vo.x : 0.f;
  vo.y = fmaf(a.y, ni, bl.y); vo.y = vo.y > 0.f ? vo.y : 0.f;
  vo.z = fmaf(a.z, ni, bl.z); vo.z = vo.z > 0.f ? vo.z : 0.f;
  vo.w = fmaf(a.w, ni, bl.w); vo.w = vo.w > 0.f ? vo.w : 0.f;

  if (fuse){
    int slot = wave*4 + v;
    *(fl4*)&xsl[slot*68 + 4*u] = vo;    // same-wave write->read: lgkm-ordered
    fl4 hacc = {0.f,0.f,0.f,0.f};
    #pragma unroll 4
    for (int k4=0;k4<16;k4++){
      fl4 xv = *(fl4*)&xsl[slot*68 + 4*k4];
      #pragma unroll
      for (int j=0;j<4;j++){
        float xk = j==0?xv.x:(j==1?xv.y:(j==2?xv.z:xv.w));
        fl4 wv = *(fl4*)&Wsl[(4*k4+j)*64 + 4*u];
        hacc.x = fmaf(xk, wv.x, hacc.x); hacc.y = fmaf(xk, wv.y, hacc.y);
        hacc.z = fmaf(xk, wv.z, hacc.z); hacc.w = fmaf(xk, wv.w, hacc.w);
      }
    }
    hgat[(size_t)node*16 + u] = f8pack4(hacc.x, hacc.y, hacc.z, hacc.w);
    fl4 a4 = *(const fl4*)&al[g*64 + 4*u];
    fl4 r4 = *(const fl4*)&ar[g*64 + 4*u];
    float elp = hacc.x*a4.x + hacc.y*a4.y + hacc.z*a4.z + hacc.w*a4.w;
    float erp = hacc.x*r4.x + hacc.y*r4.y + hacc.z*r4.z + hacc.w*r4.w;
    elp += __shfl_xor(elp,1); elp += __shfl_xor(elp,2);
    elp += __shfl_xor(elp,4); elp += __shfl_xor(elp,8);
    erp += __shfl_xor(erp,1); erp += __shfl_xor(erp,2);
    erp += __shfl_xor(erp,4); erp += __shfl_xor(erp,8);
    if (u == 0){
      fg[EL_OFF + node] = elp;
      fg[ER_OFF + node] = erp;
    }
  }

  // readout: sum/max across the wave's 4 nodes (groups) once
  fl4 vs = vo, vm = vo;
  vs.x += __shfl_xor(vs.x,16); vs.x += __shfl_xor(vs.x,32);
  vs.y += __shfl_xor(vs.y,16); vs.y += __shfl_xor(vs.y,32);
  vs.z += __shfl_xor(vs.z,16); vs.z += __shfl_xor(vs.z,32);
  vs.w += __shfl_xor(vs.w,16); vs.w += __shfl_xor(vs.w,32);
  vm.x = fmaxf(vm.x, __shfl_xor(vm.x,16)); vm.x = fmaxf(vm.x, __shfl_xor(vm.x,32));
  vm.y = fmaxf(vm.y, __shfl_xor(vm.y,16)); vm.y = fmaxf(vm.y, __shfl_xor(vm.y,32));
  vm.z = fmaxf(vm.z, __shfl_xor(vm.z,16)); vm.z = fmaxf(vm.z, __shfl_xor(vm.z,32));
  vm.w = fmaxf(vm.w, __shfl_xor(vm.w,16)); vm.w = fmaxf(vm.w, __shfl_xor(vm.w,32));
  if (lane < 16){
    ((fl4*)ssum[wave])[u] = vs;
    ((fl4*)smx[wave])[u]  = vm;
  }
  __syncthreads();
  if (threadIdx.x < 64){
    int t = threadIdx.x;
    float s = ssum[0][t]+ssum[1][t]+ssum[2][t]+ssum[3][t];
    float mx = fmaxf(fmaxf(smx[0][t],smx[1][t]), fmaxf(smx[2][t],smx[3][t]));
    atomicAdd(&sm[g*64 + t], s);
    atomicMax((int*)sm + 192 + g*64 + t, __float_as_int(mx));  // v>=0: int order == float order
  }
}

// readout finalize + cross-graph feature exchange + supernode h_gat row, el[N].
// Re-zeroes its source graph's sm slots (read-then-zero, block-exclusive).
__global__ void k_exchange(float* fb, float* sm, const float* Wx, const float* bx,
                           const float* Wgat, const float* al, int it) {
  int gt = blockIdx.x;     // target graph
  int t = threadIdx.x;     // 64 threads
  int src, widx;
  if ((it & 1) == 0){ src = (gt==0)?1:(gt==1)?2:0; widx = (gt==0)?1:(gt==1)?0:2; }
  else              { src = (gt==0)?2:(gt==1)?0:1; widx = (gt==0)?5:(gt==1)?3:4; }
  __shared__ float ro[128];
  __shared__ float f[64];
  __shared__ float red[64];
  __shared__ float hsb[64];
  ro[t]      = sm[src*64 + t] * (1.0f/(float)N);
  ro[64 + t] = __int_as_float(((int*)sm)[192 + src*64 + t]);
  sm[src*64 + t] = 0.f;                    // exclusive: only this block reads src
  ((int*)sm)[192 + src*64 + t] = 0;
  __syncthreads();
  float a = bx[widx*64 + t];
  for (int k=0;k<128;k++) a = fmaf(ro[k], Wx[(size_t)widx*8192 + k*64 + t], a);
  a = a > 0.f ? a : 0.f;
  f[t] = a;
  __syncthreads();
  float* fg = fb + (size_t)gt*GF;
  float hs = 0.f;
  for (int k=0;k<64;k++) hs = fmaf(f[k], Wgat[(size_t)gt*4096 + k*64 + t], hs);
  hsb[t] = hs;
  red[t] = hs * al[gt*64 + t];
  __syncthreads();
  if (t < 16){
    uint_t r = f8pack4(hsb[4*t], hsb[4*t+1], hsb[4*t+2], hsb[4*t+3]);
    ((uint_t*)(fg + X_OFF))[(size_t)N*16 + t] = r;       // supernode h_gat row
  }
  if (t == 0){
    float e = 0.f;
    for (int k=0;k<64;k++) e += red[k];
    fg[EL_OFF + N] = e;                      // el for supernode
  }
}

// GAT aggregation with fused online softmax AND the next GCN dense layer.
__global__ __launch_bounds__(256) void k_gat_agg(float* fb, uchar_t* hb, const int* ib,
    const float* bgat, const float* Wc0, const float* Wc1, const float* Wc2, int lay) {
  int g, blk;
  swz_tile(blockIdx.x, g, blk);
  float* fg = fb + (size_t)g*GF;
  const uint_t* hu = (const uint_t*)(fg + X_OFF);         // h_gat (read)
  uint_t* hout = (uint_t*)(hb + (size_t)g*GH);            // h_gcn (write)
  const int* ig = ib + (size_t)g*GI;
  int wave = threadIdx.x >> 6, lane = threadIdx.x & 63;
  int v = lane >> 4, u = lane & 15;
  int base = lane & 48;
  int w = blk*4 + wave;
  int node = w + NWAVE*v;
  const int* rp = ig + RP_OFF;
  const int* ss = ig + SS_OFF;
  const float* el = fg + EL_OFF;
  fl4 bg = ((const fl4*)(bgat + g*64))[u];
  __shared__ float Wsl[4096];
  __shared__ float xsl[16*68];
  {
    const float* W = (g==0?Wc0:(g==1?Wc1:Wc2)) + (size_t)lay*4096;
    for (int i=threadIdx.x;i<4096;i+=256) Wsl[i] = W[i];
  }
  __syncthreads();
  fl4 supf = f8up4(hu[(size_t)N*16 + u]);

  int s0 = rp[node], s1 = rp[node+1];
  if (s1 > E) s1 = E;                  // defensive bound
  if (s0 > s1) s0 = s1;
  float ern = fg[ER_OFF + node];
  float eln = el[node];
  float elsup = el[N];
  float es = eln + ern;   es = es >= 0.f ? es : 0.2f*es;  float ts = __expf(es);
  float eu = elsup + ern; eu = eu >= 0.f ? eu : 0.2f*eu;  float tu = __expf(eu);
  fl4 fs = f8up4(hu[(size_t)node*16 + u]);
  fl4 a;
  a.x = fmaf(tu, supf.x, ts*fs.x);
  a.y = fmaf(tu, supf.y, ts*fs.y);
  a.z = fmaf(tu, supf.z, ts*fs.z);
  a.w = fmaf(tu, supf.w, ts*fs.w);
  float esum = 0.f;

  int idxv; float elv;
  { int ei = s0 + u;
    int ec = ei < s1 ? ei : (s0 < s1 ? s0 : 0);           // always a valid slot
    idxv = __builtin_nontemporal_load(&ss[ec]); }
  elv = el[idxv];                                         // safe: idxv in [0,N)

  for (int kb = s0; kb < s1; kb += 16){                   // group-divergent loop
    float xe = elv + ern; xe = xe >= 0.f ? xe : 0.2f*xe;
    float ex = __expf(xe);
    float wv = (kb + u) < s1 ? ex : 0.f;
    esum += wv;
    uint_t vv[16];
    #pragma unroll
    for (int j=0;j<16;j++){
      int ij = __shfl(idxv, base + j);
      vv[j] = hu[(size_t)ij*16 + u];
    }
    int kn = kb + 16;
    if (kn < s1){                                         // prefetch next round
      int ei = kn + u; int ec = ei < s1 ? ei : s0;
      idxv = __builtin_nontemporal_load(&ss[ec]);
      elv = el[idxv];
    }
    #pragma unroll
    for (int j=0;j<16;j++){
      float wj = __shfl(wv, base + j);                    // already zero-masked
      fl4 f = f8up4(vv[j]);
      a.x = fmaf(wj, f.x, a.x); a.y = fmaf(wj, f.y, a.y);
      a.z = fmaf(wj, f.z, a.z); a.w = fmaf(wj, f.w, a.w);
    }
  }

  esum += __shfl_xor(esum,1); esum += __shfl_xor(esum,2);
  esum += __shfl_xor(esum,4); esum += __shfl_xor(esum,8);
  float is = 1.0f / (esum + ts + tu);

  fl4 vo;                                                 // GAT output (no relu)
  vo.x = fmaf(a.x, is, bg.x); vo.y = fmaf(a.y, is, bg.y);
  vo.z = fmaf(a.z, is, bg.z); vo.w = fmaf(a.w, is, bg.w);

  // fused next-layer GCN dense: h_gcn = fp8((vo @ Wc[lay]) * no[node])
  int slot = wave*4 + v;
  *(fl4*)&xsl[slot*68 + 4*u] = vo;
  fl4 hacc = {0.f,0.f,0.f,0.f};
  #pragma unroll 4
  for (int k4=0;k4<16;k4++){
    fl4 xv = *(fl4*)&xsl[slot*68 + 4*k4];
    #pragma unroll
    for (int j=0;j<4;j++){
      float xk = j==0?xv.x:(j==1?xv.y:(j==2?xv.z:xv.w));
      fl4 wv = *(fl4*)&Wsl[(4*k4+j)*64 + 4*u];
      hacc.x = fmaf(xk, wv.x, hacc.x); hacc.y = fmaf(xk, wv.y, hacc.y);
      hacc.z = fmaf(xk, wv.z, hacc.z); hacc.w = fmaf(xk, wv.w, hacc.w);
    }
  }
  float no = fg[NO_OFF + node];
  hout[(size_t)node*16 + u] = f8pack4(hacc.x*no, hacc.y*no, hacc.z*no, hacc.w*no);
}

__global__ __launch_bounds__(384) void k_mlp(const float* sm, const float* W1, const float* b1,
    const float* W2, const float* b2, const float* W3, const float* b3, float* out) {
  __shared__ float nf[384];
  __shared__ float y1[192];
  __shared__ float y2[96];
  __shared__ float z[2];
  int t = threadIdx.x;
  int g = t / 128, j = t % 128;
  nf[t] = (j < 64) ? sm[g*64 + j] * (1.0f/(float)N)
                   : __int_as_float(((const int*)sm)[192 + g*64 + (j-64)]);
  __syncthreads();
  if (t < 192){
    float a = b1[t];
    for (int k=0;k<384;k++) a = fmaf(nf[k], W1[(size_t)k*192 + t], a);
    y1[t] = a > 0.f ? a : 0.f;
  }
  __syncthreads();
  if (t < 96){
    float a = b2[t];
    for (int k=0;k<192;k++) a = fmaf(y1[k], W2[(size_t)k*96 + t], a);
    y2[t] = a > 0.f ? a : 0.f;
  }
  __syncthreads();
  if (t < 2){
    float a = b3[t];
    for (int k=0;k<96;k++) a = fmaf(y2[k], W3[k*2 + t], a);
    z[t] = a;
  }
  __syncthreads();
  if (t == 0){
    float m = fmaxf(z[0], z[1]);
    float l = m + logf(__expf(z[0]-m) + __expf(z[1]-m));
    out[0] = z[0] - l;
    out[1] = z[1] - l;
  }
}

extern "C" void kernel_launch(void* const* d_in, const int* in_sizes, int n_in,
                              void* d_out, int out_size, void* d_ws, size_t ws_size,
                              hipStream_t stream) {
  const float* x_s  = (const float*)d_in[0];
  const float* x_g  = (const float*)d_in[1];
  const float* x_t  = (const float*)d_in[2];
  const float* Wc_s = (const float*)d_in[3];
  const float* bc_s = (const float*)d_in[4];
  const float* Wc_g = (const float*)d_in[5];
  const float* bc_g = (const float*)d_in[6];
  const float* Wc_t = (const float*)d_in[7];
  const float* bc_t = (const float*)d_in[8];
  const float* Wx   = (const float*)d_in[9];
  const float* bx   = (const float*)d_in[10];
  const float* Wgat = (const float*)d_in[11];
  const float* al   = (const float*)d_in[12];
  const float* ar   = (const float*)d_in[13];
  const float* bgat = (const float*)d_in[14];
  const float* W1   = (const float*)d_in[15];
  const float* b1   = (const float*)d_in[16];
  const float* W2   = (const float*)d_in[17];
  const float* b2   = (const float*)d_in[18];
  const float* W3   = (const float*)d_in[19];
  const float* b3   = (const float*)d_in[20];
  const int* src_s  = (const int*)d_in[21];
  const int* dst_s  = (const int*)d_in[22];
  const int* src_g  = (const int*)d_in[23];
  const int* dst_g  = (const int*)d_in[24];
  const int* src_t  = (const int*)d_in[25];
  const int* dst_t  = (const int*)d_in[26];

  float* fb = (float*)d_ws;
  int*   ib = (int*)(fb + 3*GF);
  uchar_t* hb = (uchar_t*)(ib + 3*GI);
  float* sm = (float*)(hb + 3*GH);
  int*   pt = (int*)(sm + 384);              // 3*SCB scan partials
  int*   parts_ct = pt + 3*SCB + 64;         // 3*BPR*N
  int*   parts_no = parts_ct + (size_t)3*BPR*N;
  int*   off      = parts_no + (size_t)3*BPR*N;
  float* out = (float*)d_out;

  dim3 b256(256);
  int mmb = (N+63)/64;

  // graph prep: LDS-histogram counting sort (write-localized, no global atomics)
  k_hist      <<<dim3(BPR, RNG, 3),  dim3(1024), 0, stream>>>(parts_ct, parts_no, src_s,dst_s, src_g,dst_g, src_t,dst_t);
  k_scan_local<<<dim3(SCB, 3),       dim3(1024), 0, stream>>>(ib, pt, parts_ct);
  k_scan_part <<<dim3(3),              dim3(64), 0, stream>>>(pt);
  k_scan_apply<<<dim3(SCB, 3),       dim3(1024), 0, stream>>>(fb, ib, pt, parts_no);
  k_slice_off <<<dim3((N+255)/256, 3),     b256, 0, stream>>>(ib, parts_ct, off);
  k_scatter_r <<<dim3(BPR, RNG, 3),  dim3(1024), 0, stream>>>(ib, off, src_s,dst_s, src_g,dst_g, src_t,dst_t);

  // initial GCN dense from input x (x never materialized in ws)
  k_mm_gcn0 <<<dim3(mmb, 3), b256, 0, stream>>>(fb, hb, x_s, x_g, x_t,
                                                Wc_s, Wc_g, Wc_t, sm);

  for (int it = 0; it < 2; ++it) {
    k_gcn_agg <<<dim3(3*AGB), b256, 0, stream>>>(fb, hb, ib, bc_s, bc_g, bc_t, it, sm,
                                                 Wgat, al, ar, 1);
    k_exchange<<<dim3(3), dim3(64), 0, stream>>>(fb, sm, Wx, bx, Wgat, al, it);
    k_gat_agg <<<dim3(3*AGB), b256, 0, stream>>>(fb, hb, ib, bgat,
                                                 Wc_s, Wc_g, Wc_t, it+1);
  }

  // final layer readout (no fusion) + MLP head
  k_gcn_agg <<<dim3(3*AGB), b256, 0, stream>>>(fb, hb, ib, bc_s, bc_g, bc_t, 2, sm,
                                               Wgat, al, ar, 0);
  k_mlp     <<<1, 384, 0, stream>>>(sm, W1, b1, W2, b2, W3, b3, out);
}

// Round 11
// 683.801 us; speedup vs baseline: 1.4798x; 1.0627x over previous
//
#include <hip/hip_runtime.h>
#include <math.h>

constexpr int N = 50000;
constexpr int E = 800000;
constexpr int H = 64;
constexpr int NWAVE = 12500;          // node stride between a wave's 4 groups
constexpr int AGB = 3125;             // agg blocks (tiles) per graph
constexpr int SCB = 49;               // scan blocks per graph: 49*1024 >= N
constexpr int RNG = 4;                // histogram ranges per graph (was 8; u16 packing)
constexpr int BPR = 16;               // edge slices per graph (was 8)
constexpr int BINS = N / RNG;         // 12500 bins per range
constexpr int HBW  = BINS / 2;        // 6250 packed u32 words per hist array
constexpr int NP   = N / 2;           // 25000 packed words per (graph,slice)
constexpr int ES   = E / BPR;         // 50000 edges per slice

// XCD-affinity swizzle constants (stateless, replay-safe).
constexpr int FULLR = AGB / 3;        // 1041 full rounds
constexpr int FULLB = FULLR * 8;      // 8328 bids in full rounds
constexpr int G2F   = FULLR * 2;      // 2082 g2 tiles from full rounds
constexpr int REM0  = AGB - 3*FULLR;  // 2 leftover g0 tiles
static_assert(3*FULLR + REM0 == AGB, "g0 cover");
static_assert(2*FULLR + (3*AGB - FULLB - 2*REM0) == AGB, "g2 cover");
static_assert(BPR*N == E, "off fits PAD region exactly");

typedef unsigned short ushort_t;
typedef unsigned int uint_t;
typedef unsigned char uchar_t;
typedef float fl2 __attribute__((ext_vector_type(2)));
typedef float fl4 __attribute__((ext_vector_type(4)));

// ---- workspace layout (element offsets) ----
// X region holds the per-graph fp8 h_gat table ((N+1)*64 B).
constexpr size_t X_OFF    = 0;                          // h_gat table (fp8)
constexpr size_t NO_OFF   = X_OFF + (size_t)N*H;        // N   deg_out^-1/2
constexpr size_t NI_OFF   = NO_OFF + N;                 // N   deg_in^-1/2
constexpr size_t EL_OFF   = NI_OFF + N;                 // N+1 GAT el (incl supernode)
constexpr size_t ER_OFF   = EL_OFF + (N+1);             // N   GAT er
constexpr size_t PAD_OFF  = ER_OFF + N;                 // E ints: per-graph off[] (slice scatter bases)
constexpr size_t GF = ((PAD_OFF + E + 3*N + 255)/256)*256;

constexpr size_t RP_OFF = 0;                            // N+1 row_ptr (CSR by dst)
constexpr size_t CT_OFF = RP_OFF + (N+1);               // N   in-degree count
constexpr size_t SS_OFF = CT_OFF + N;                   // E   src sorted by dst
constexpr size_t GI = ((SS_OFF + E + 255)/256)*256;

// per-graph fp8 h_gcn block: 64 B per row; row N = supernode (unused for gcn)
constexpr size_t GH = (size_t)(N+1)*64;                 // bytes

// fp8 helpers: HW RNE pack/unpack (OCP e4m3 on gfx950)
__device__ inline uint_t f8pack4(float a, float b, float c, float d){
  int r = __builtin_amdgcn_cvt_pk_fp8_f32(a, b, 0, false);
  r = __builtin_amdgcn_cvt_pk_fp8_f32(c, d, r, true);
  return (uint_t)r;
}
__device__ inline fl4 f8up4(uint_t v){
  fl2 lo = __builtin_amdgcn_cvt_pk_f32_fp8((int)v, false);
  fl2 hi = __builtin_amdgcn_cvt_pk_f32_fp8((int)v, true);
  fl4 r; r.x = lo.x; r.y = lo.y; r.z = hi.x; r.w = hi.y;
  return r;
}

// Deterministic bid -> (graph, tile) swizzle for XCD L2 affinity.
__device__ inline void swz_tile(int bid, int& g, int& b){
  if (bid < FULLB){
    int r = bid >> 3, s = bid & 7;
    if (s < 3){ g = 0; b = r*3 + s; }
    else if (s < 6){ g = 1; b = r*3 + (s-3); }
    else { g = 2; b = r*2 + (s-6); }
  } else {
    int t = bid - FULLB;
    if (t < REM0){ g = 0; b = 3*FULLR + t; }
    else if (t < 2*REM0){ g = 1; b = 3*FULLR + (t-REM0); }
    else { g = 2; b = G2F + (t-2*REM0); }
  }
}

// ---- prep: range-partitioned LDS histograms, u16-packed (RNG halved 8->4:
// edge re-read traffic and LDS atomic count halve; write-localized scatter
// kept — R9 proved scattered global stores cost 16x write amplification) ----
__global__ __launch_bounds__(1024) void k_hist(uint_t* parts_ct, uint_t* parts_no,
    const int* s0,const int* d0,const int* s1,const int* d1,const int* s2,const int* d2) {
  int sl = blockIdx.x, r = blockIdx.y, g = blockIdx.z;
  const int* s = g==0?s0:(g==1?s1:s2);
  const int* d = g==0?d0:(g==1?d1:d2);
  __shared__ uint_t hc[HBW];     // nodes 2i,2i+1 packed lo/hi u16
  __shared__ uint_t hn[HBW];
  for (int i=threadIdx.x;i<HBW;i+=1024){ hc[i]=0u; hn[i]=0u; }
  __syncthreads();
  int lo = r*BINS, hi = lo+BINS;
  int e0 = sl*ES, e1 = e0+ES;
  for (int e=e0+threadIdx.x; e<e1; e+=1024){
    int ds = d[e], sr = s[e];
    if (ds>=lo && ds<hi){ int n = ds-lo; atomicAdd(&hc[n>>1], 1u<<((n&1)<<4)); }
    if (sr>=lo && sr<hi){ int n = sr-lo; atomicAdd(&hn[n>>1], 1u<<((n&1)<<4)); }
  }
  __syncthreads();
  size_t base = ((size_t)g*BPR + sl)*NP + (lo>>1);
  for (int i=threadIdx.x;i<HBW;i+=1024){
    parts_ct[base+i]=hc[i];
    parts_no[base+i]=hn[i];
  }
}

// ---- hierarchical exclusive scan of cnt -> rp (all parallel) ----
__global__ __launch_bounds__(1024) void k_scan_local(int* ib, int* pt, const uint_t* parts_ct) {
  int g = blockIdx.y;
  int* ig = ib + (size_t)g*GI;
  int i = blockIdx.x*1024 + threadIdx.x;
  int c = 0;
  if (i < N){
    int sh16 = (i&1)<<4;
    #pragma unroll
    for (int s=0;s<BPR;s++){
      uint_t w = parts_ct[((size_t)g*BPR+s)*NP + (i>>1)];
      c += (int)((w >> sh16) & 0xFFFFu);
    }
    ig[CT_OFF + i] = c;
  }
  __shared__ int sh[1024];
  sh[threadIdx.x] = c; __syncthreads();
  #pragma unroll
  for (int off=1; off<1024; off<<=1){
    int t = (threadIdx.x>=off) ? sh[threadIdx.x-off] : 0;
    __syncthreads();
    sh[threadIdx.x] += t;
    __syncthreads();
  }
  if (i < N) ig[RP_OFF + i] = sh[threadIdx.x] - c;       // local exclusive
  if (threadIdx.x == 1023) pt[g*SCB + blockIdx.x] = sh[1023];
}

__global__ void k_scan_part(int* pt) {
  int g = blockIdx.x;
  __shared__ int sh[SCB];
  int t = threadIdx.x;
  if (t < SCB) sh[t] = pt[g*SCB + t];
  __syncthreads();
  if (t == 0){
    int run = 0;
    for (int b=0;b<SCB;b++){ int c = sh[b]; sh[b] = run; run += c; }
  }
  __syncthreads();
  if (t < SCB) pt[g*SCB + t] = sh[t];
}

__global__ __launch_bounds__(1024) void k_scan_apply(float* fb, int* ib, const int* pt,
                                                     const uint_t* parts_no) {
  int g = blockIdx.y;
  float* fg = fb + (size_t)g*GF;
  int* ig = ib + (size_t)g*GI;
  int i = blockIdx.x*1024 + threadIdx.x;
  if (i >= N) return;
  int base = pt[g*SCB + blockIdx.x];
  int r = ig[RP_OFF + i] + base;
  ig[RP_OFF + i] = r;
  int c = ig[CT_OFF + i];
  int o = 0;
  int sh16 = (i&1)<<4;
  #pragma unroll
  for (int s=0;s<BPR;s++){
    uint_t w = parts_no[((size_t)g*BPR+s)*NP + (i>>1)];
    o += (int)((w >> sh16) & 0xFFFFu);
  }
  fg[NI_OFF + i] = rsqrtf((float)(c+1));                 // +1 self loop
  fg[NO_OFF + i] = rsqrtf((float)(o+1));
  if (i == N-1) ig[RP_OFF + N] = r + c;
}

// per-(slice,node) exclusive prefix over slices -> exact scatter offsets
// (off lives in the per-graph PAD region of fb: BPR*N == E ints exactly).
__global__ __launch_bounds__(256) void k_slice_off(float* fb, const int* ib,
                                                   const uint_t* parts_ct) {
  int g = blockIdx.y;
  int i = blockIdx.x*256 + threadIdx.x;
  if (i >= N) return;
  int* offg = (int*)(fb + (size_t)g*GF + PAD_OFF);
  int base = ib[(size_t)g*GI + RP_OFF + i];
  int sh16 = (i&1)<<4;
  #pragma unroll
  for (int s=0;s<BPR;s++){
    offg[(size_t)s*N + i] = base;
    uint_t w = parts_ct[((size_t)g*BPR+s)*NP + (i>>1)];
    base += (int)((w >> sh16) & 0xFFFFu);
  }
}

// scatter: LDS cursors per range; writes confined to an L2-resident window
// per (slice,range) block and written exactly once (no global atomics).
__global__ __launch_bounds__(1024) void k_scatter_r(float* fb, int* ib,
    const int* s0,const int* d0,const int* s1,const int* d1,const int* s2,const int* d2) {
  int sl = blockIdx.x, r = blockIdx.y, g = blockIdx.z;
  const int* s = g==0?s0:(g==1?s1:s2);
  const int* d = g==0?d0:(g==1?d1:d2);
  int* ss = ib + (size_t)g*GI + SS_OFF;
  const int* offg = (const int*)(fb + (size_t)g*GF + PAD_OFF);
  __shared__ int cur[BINS];            // 12500 ints = 50KB
  int lo = r*BINS;
  for (int i=threadIdx.x;i<BINS;i+=1024) cur[i] = offg[(size_t)sl*N + lo + i];
  __syncthreads();
  int e0 = sl*ES, e1 = e0+ES;
  for (int e=e0+threadIdx.x; e<e1; e+=1024){
    int ds = d[e];
    if (ds>=lo && ds<lo+BINS){
      int pos = atomicAdd(&cur[ds-lo],1);
      ss[pos] = s[e];
    }
  }
}

// Initial GCN dense layer: reads INPUT x directly (x never staged to ws).
__global__ __launch_bounds__(256) void k_mm_gcn0(float* fb, uchar_t* hb,
    const float* x0,const float* x1,const float* x2,
    const float* W0,const float* W1,const float* W2, float* sm) {
  if (blockIdx.x==0 && blockIdx.y==0){
    for (int i=threadIdx.x;i<384;i+=256) sm[i]=0.f;
  }
  int g = blockIdx.y;
  const float* W = g==0?W0:(g==1?W1:W2);
  const float* x = g==0?x0:(g==1?x1:x2);
  __shared__ float Ws[64*64];
  __shared__ float Xs[64*65];
  float* fg = fb + (size_t)g*GF;
  int row0 = blockIdx.x*64;
  for (int i=threadIdx.x; i<4096; i+=256) Ws[i] = W[i];
  int r = threadIdx.x>>2, q = threadIdx.x&3;
  int row = row0 + r;
  int rowc = row < N ? row : N-1;
  {
    const float4* xr = (const float4*)(x + (size_t)rowc*64) + q*4;
    float* xd = Xs + r*65 + q*16;
    #pragma unroll
    for (int c=0;c<4;c++){ float4 v = xr[c]; xd[4*c]=v.x; xd[4*c+1]=v.y; xd[4*c+2]=v.z; xd[4*c+3]=v.w; }
  }
  __syncthreads();
  float acc[16];
  #pragma unroll
  for (int j=0;j<16;j++) acc[j]=0.f;
  const float* xrow = Xs + r*65;
  #pragma unroll 8
  for (int k=0;k<64;k++){
    float xk = xrow[k];
    const float* wr = Ws + k*64 + q*16;
    #pragma unroll
    for (int j=0;j<16;j++) acc[j] = fmaf(xk, wr[j], acc[j]);
  }
  if (row >= N) return;
  float sc = fg[NO_OFF + row];
  uint_t pk[4];
  #pragma unroll
  for (int j=0;j<4;j++)
    pk[j] = f8pack4(acc[4*j]*sc, acc[4*j+1]*sc, acc[4*j+2]*sc, acc[4*j+3]*sc);
  *(uint4*)(hb + (size_t)g*GH + (size_t)row*64 + q*16) = *(const uint4*)pk;
}

// GCN aggregate, group-per-node, FUSED with the GAT dense layer. (control)
__global__ __launch_bounds__(256) void k_gcn_agg(float* fb, const uchar_t* hb, const int* ib,
    const float* b0, const float* b1, const float* b2, int lay, float* sm,
    const float* Wgat, const float* al, const float* ar, int fuse) {
  int g, blk;
  swz_tile(blockIdx.x, g, blk);
  const float* b = (g==0?b0:(g==1?b1:b2)) + lay*64;
  float* fg = fb + (size_t)g*GF;
  const uint_t* hu = (const uint_t*)(hb + (size_t)g*GH);  // h_gcn (read)
  uint_t* hgat = (uint_t*)(fg + X_OFF);                   // h_gat (write)
  const int* ig = ib + (size_t)g*GI;
  int wave = threadIdx.x >> 6, lane = threadIdx.x & 63;
  int v = lane >> 4, u = lane & 15;
  int base = lane & 48;
  int w = blk*4 + wave;
  int node = w + NWAVE*v;
  const int* rp = ig + RP_OFF;
  const int* ss = ig + SS_OFF;
  fl4 bl = ((const fl4*)b)[u];
  __shared__ float Wsl[4096];
  __shared__ float xsl[16*68];          // padded stride 68: bank-spread slots
  __shared__ float ssum[4][64];
  __shared__ float smx[4][64];
  if (fuse){
    const float* Wg = Wgat + (size_t)g*4096;
    for (int i=threadIdx.x;i<4096;i+=256) Wsl[i] = Wg[i];
  }
  __syncthreads();

  int s0 = rp[node], s1 = rp[node+1];
  if (s1 > E) s1 = E;                  // defensive bound
  if (s0 > s1) s0 = s1;
  float ni = fg[NI_OFF + node];
  fl4 a = f8up4(hu[(size_t)node*16 + u]);                 // self loop (pre-scaled)
  int idxv;
  { int ei = s0 + u; int ec = ei < s1 ? ei : (s0 < s1 ? s0 : 0);
    idxv = __builtin_nontemporal_load(&ss[ec]); }

  for (int kb = s0; kb < s1; kb += 16){                   // group-divergent loop
    uint_t vv[16];
    #pragma unroll
    for (int j=0;j<16;j++){
      int ij = __shfl(idxv, base + j);
      vv[j] = hu[(size_t)ij*16 + u];
    }
    int kn = kb + 16;
    if (kn < s1){                                         // prefetch next round
      int ei = kn + u; int ec = ei < s1 ? ei : s0;
      idxv = __builtin_nontemporal_load(&ss[ec]);
    }
    #pragma unroll
    for (int j=0;j<16;j++){
      float wj = (kb + j) < s1 ? 1.f : 0.f;
      fl4 f = f8up4(vv[j]);
      a.x = fmaf(wj, f.x, a.x); a.y = fmaf(wj, f.y, a.y);
      a.z = fmaf(wj, f.z, a.z); a.w = fmaf(wj, f.w, a.w);
    }
  }

  fl4 vo;
  vo.x = fmaf(a.x, ni, bl.x); vo.x = vo.x > 0.f ? vo.x : 0.f;
  vo.y = fmaf(a.y, ni, bl.y); vo.y = vo.y > 0.f ? vo.y : 0.f;
  vo.z = fmaf(a.z, ni, bl.z); vo.z = vo.z > 0.f ? vo.z : 0.f;
  vo.w = fmaf(a.w, ni, bl.w); vo.w = vo.w > 0.f ? vo.w : 0.f;

  if (fuse){
    int slot = wave*4 + v;
    *(fl4*)&xsl[slot*68 + 4*u] = vo;    // same-wave write->read: lgkm-ordered
    fl4 hacc = {0.f,0.f,0.f,0.f};
    #pragma unroll 4
    for (int k4=0;k4<16;k4++){
      fl4 xv = *(fl4*)&xsl[slot*68 + 4*k4];
      #pragma unroll
      for (int j=0;j<4;j++){
        float xk = j==0?xv.x:(j==1?xv.y:(j==2?xv.z:xv.w));
        fl4 wv = *(fl4*)&Wsl[(4*k4+j)*64 + 4*u];
        hacc.x = fmaf(xk, wv.x, hacc.x); hacc.y = fmaf(xk, wv.y, hacc.y);
        hacc.z = fmaf(xk, wv.z, hacc.z); hacc.w = fmaf(xk, wv.w, hacc.w);
      }
    }
    hgat[(size_t)node*16 + u] = f8pack4(hacc.x, hacc.y, hacc.z, hacc.w);
    fl4 a4 = *(const fl4*)&al[g*64 + 4*u];
    fl4 r4 = *(const fl4*)&ar[g*64 + 4*u];
    float elp = hacc.x*a4.x + hacc.y*a4.y + hacc.z*a4.z + hacc.w*a4.w;
    float erp = hacc.x*r4.x + hacc.y*r4.y + hacc.z*r4.z + hacc.w*r4.w;
    elp += __shfl_xor(elp,1); elp += __shfl_xor(elp,2);
    elp += __shfl_xor(elp,4); elp += __shfl_xor(elp,8);
    erp += __shfl_xor(erp,1); erp += __shfl_xor(erp,2);
    erp += __shfl_xor(erp,4); erp += __shfl_xor(erp,8);
    if (u == 0){
      fg[EL_OFF + node] = elp;
      fg[ER_OFF + node] = erp;
    }
  }

  // readout: sum/max across the wave's 4 nodes (groups) once
  fl4 vs = vo, vm = vo;
  vs.x += __shfl_xor(vs.x,16); vs.x += __shfl_xor(vs.x,32);
  vs.y += __shfl_xor(vs.y,16); vs.y += __shfl_xor(vs.y,32);
  vs.z += __shfl_xor(vs.z,16); vs.z += __shfl_xor(vs.z,32);
  vs.w += __shfl_xor(vs.w,16); vs.w += __shfl_xor(vs.w,32);
  vm.x = fmaxf(vm.x, __shfl_xor(vm.x,16)); vm.x = fmaxf(vm.x, __shfl_xor(vm.x,32));
  vm.y = fmaxf(vm.y, __shfl_xor(vm.y,16)); vm.y = fmaxf(vm.y, __shfl_xor(vm.y,32));
  vm.z = fmaxf(vm.z, __shfl_xor(vm.z,16)); vm.z = fmaxf(vm.z, __shfl_xor(vm.z,32));
  vm.w = fmaxf(vm.w, __shfl_xor(vm.w,16)); vm.w = fmaxf(vm.w, __shfl_xor(vm.w,32));
  if (lane < 16){
    ((fl4*)ssum[wave])[u] = vs;
    ((fl4*)smx[wave])[u]  = vm;
  }
  __syncthreads();
  if (threadIdx.x < 64){
    int t = threadIdx.x;
    float s = ssum[0][t]+ssum[1][t]+ssum[2][t]+ssum[3][t];
    float mx = fmaxf(fmaxf(smx[0][t],smx[1][t]), fmaxf(smx[2][t],smx[3][t]));
    atomicAdd(&sm[g*64 + t], s);
    atomicMax((int*)sm + 192 + g*64 + t, __float_as_int(mx));  // v>=0: int order == float order
  }
}

// readout finalize + cross-graph feature exchange + supernode h_gat row, el[N].
// Re-zeroes its source graph's sm slots (read-then-zero, block-exclusive).
__global__ void k_exchange(float* fb, float* sm, const float* Wx, const float* bx,
                           const float* Wgat, const float* al, int it) {
  int gt = blockIdx.x;     // target graph
  int t = threadIdx.x;     // 64 threads
  int src, widx;
  if ((it & 1) == 0){ src = (gt==0)?1:(gt==1)?2:0; widx = (gt==0)?1:(gt==1)?0:2; }
  else              { src = (gt==0)?2:(gt==1)?0:1; widx = (gt==0)?5:(gt==1)?3:4; }
  __shared__ float ro[128];
  __shared__ float f[64];
  __shared__ float red[64];
  __shared__ float hsb[64];
  ro[t]      = sm[src*64 + t] * (1.0f/(float)N);
  ro[64 + t] = __int_as_float(((int*)sm)[192 + src*64 + t]);
  sm[src*64 + t] = 0.f;                    // exclusive: only this block reads src
  ((int*)sm)[192 + src*64 + t] = 0;
  __syncthreads();
  float a = bx[widx*64 + t];
  for (int k=0;k<128;k++) a = fmaf(ro[k], Wx[(size_t)widx*8192 + k*64 + t], a);
  a = a > 0.f ? a : 0.f;
  f[t] = a;
  __syncthreads();
  float* fg = fb + (size_t)gt*GF;
  float hs = 0.f;
  for (int k=0;k<64;k++) hs = fmaf(f[k], Wgat[(size_t)gt*4096 + k*64 + t], hs);
  hsb[t] = hs;
  red[t] = hs * al[gt*64 + t];
  __syncthreads();
  if (t < 16){
    uint_t r = f8pack4(hsb[4*t], hsb[4*t+1], hsb[4*t+2], hsb[4*t+3]);
    ((uint_t*)(fg + X_OFF))[(size_t)N*16 + t] = r;       // supernode h_gat row
  }
  if (t == 0){
    float e = 0.f;
    for (int k=0;k<64;k++) e += red[k];
    fg[EL_OFF + N] = e;                      // el for supernode
  }
}

// GAT aggregation with fused online softmax AND the next GCN dense layer. (control)
__global__ __launch_bounds__(256) void k_gat_agg(float* fb, uchar_t* hb, const int* ib,
    const float* bgat, const float* Wc0, const float* Wc1, const float* Wc2, int lay) {
  int g, blk;
  swz_tile(blockIdx.x, g, blk);
  float* fg = fb + (size_t)g*GF;
  const uint_t* hu = (const uint_t*)(fg + X_OFF);         // h_gat (read)
  uint_t* hout = (uint_t*)(hb + (size_t)g*GH);            // h_gcn (write)
  const int* ig = ib + (size_t)g*GI;
  int wave = threadIdx.x >> 6, lane = threadIdx.x & 63;
  int v = lane >> 4, u = lane & 15;
  int base = lane & 48;
  int w = blk*4 + wave;
  int node = w + NWAVE*v;
  const int* rp = ig + RP_OFF;
  const int* ss = ig + SS_OFF;
  const float* el = fg + EL_OFF;
  fl4 bg = ((const fl4*)(bgat + g*64))[u];
  __shared__ float Wsl[4096];
  __shared__ float xsl[16*68];
  {
    const float* W = (g==0?Wc0:(g==1?Wc1:Wc2)) + (size_t)lay*4096;
    for (int i=threadIdx.x;i<4096;i+=256) Wsl[i] = W[i];
  }
  __syncthreads();
  fl4 supf = f8up4(hu[(size_t)N*16 + u]);

  int s0 = rp[node], s1 = rp[node+1];
  if (s1 > E) s1 = E;                  // defensive bound
  if (s0 > s1) s0 = s1;
  float ern = fg[ER_OFF + node];
  float eln = el[node];
  float elsup = el[N];
  float es = eln + ern;   es = es >= 0.f ? es : 0.2f*es;  float ts = __expf(es);
  float eu = elsup + ern; eu = eu >= 0.f ? eu : 0.2f*eu;  float tu = __expf(eu);
  fl4 fs = f8up4(hu[(size_t)node*16 + u]);
  fl4 a;
  a.x = fmaf(tu, supf.x, ts*fs.x);
  a.y = fmaf(tu, supf.y, ts*fs.y);
  a.z = fmaf(tu, supf.z, ts*fs.z);
  a.w = fmaf(tu, supf.w, ts*fs.w);
  float esum = 0.f;

  int idxv; float elv;
  { int ei = s0 + u;
    int ec = ei < s1 ? ei : (s0 < s1 ? s0 : 0);           // always a valid slot
    idxv = __builtin_nontemporal_load(&ss[ec]); }
  elv = el[idxv];                                         // safe: idxv in [0,N)

  for (int kb = s0; kb < s1; kb += 16){                   // group-divergent loop
    float xe = elv + ern; xe = xe >= 0.f ? xe : 0.2f*xe;
    float ex = __expf(xe);
    float wv = (kb + u) < s1 ? ex : 0.f;
    esum += wv;
    uint_t vv[16];
    #pragma unroll
    for (int j=0;j<16;j++){
      int ij = __shfl(idxv, base + j);
      vv[j] = hu[(size_t)ij*16 + u];
    }
    int kn = kb + 16;
    if (kn < s1){                                         // prefetch next round
      int ei = kn + u; int ec = ei < s1 ? ei : s0;
      idxv = __builtin_nontemporal_load(&ss[ec]);
      elv = el[idxv];
    }
    #pragma unroll
    for (int j=0;j<16;j++){
      float wj = __shfl(wv, base + j);                    // already zero-masked
      fl4 f = f8up4(vv[j]);
      a.x = fmaf(wj, f.x, a.x); a.y = fmaf(wj, f.y, a.y);
      a.z = fmaf(wj, f.z, a.z); a.w = fmaf(wj, f.w, a.w);
    }
  }

  esum += __shfl_xor(esum,1); esum += __shfl_xor(esum,2);
  esum += __shfl_xor(esum,4); esum += __shfl_xor(esum,8);
  float is = 1.0f / (esum + ts + tu);

  fl4 vo;                                                 // GAT output (no relu)
  vo.x = fmaf(a.x, is, bg.x); vo.y = fmaf(a.y, is, bg.y);
  vo.z = fmaf(a.z, is, bg.z); vo.w = fmaf(a.w, is, bg.w);

  // fused next-layer GCN dense: h_gcn = fp8((vo @ Wc[lay]) * no[node])
  int slot = wave*4 + v;
  *(fl4*)&xsl[slot*68 + 4*u] = vo;
  fl4 hacc = {0.f,0.f,0.f,0.f};
  #pragma unroll 4
  for (int k4=0;k4<16;k4++){
    fl4 xv = *(fl4*)&xsl[slot*68 + 4*k4];
    #pragma unroll
    for (int j=0;j<4;j++){
      float xk = j==0?xv.x:(j==1?xv.y:(j==2?xv.z:xv.w));
      fl4 wv = *(fl4*)&Wsl[(4*k4+j)*64 + 4*u];
      hacc.x = fmaf(xk, wv.x, hacc.x); hacc.y = fmaf(xk, wv.y, hacc.y);
      hacc.z = fmaf(xk, wv.z, hacc.z); hacc.w = fmaf(xk, wv.w, hacc.w);
    }
  }
  float no = fg[NO_OFF + node];
  hout[(size_t)node*16 + u] = f8pack4(hacc.x*no, hacc.y*no, hacc.z*no, hacc.w*no);
}

__global__ __launch_bounds__(384) void k_mlp(const float* sm, const float* W1, const float* b1,
    const float* W2, const float* b2, const float* W3, const float* b3, float* out) {
  __shared__ float nf[384];
  __shared__ float y1[192];
  __shared__ float y2[96];
  __shared__ float z[2];
  int t = threadIdx.x;
  int g = t / 128, j = t % 128;
  nf[t] = (j < 64) ? sm[g*64 + j] * (1.0f/(float)N)
                   : __int_as_float(((const int*)sm)[192 + g*64 + (j-64)]);
  __syncthreads();
  if (t < 192){
    float a = b1[t];
    for (int k=0;k<384;k++) a = fmaf(nf[k], W1[(size_t)k*192 + t], a);
    y1[t] = a > 0.f ? a : 0.f;
  }
  __syncthreads();
  if (t < 96){
    float a = b2[t];
    for (int k=0;k<192;k++) a = fmaf(y1[k], W2[(size_t)k*96 + t], a);
    y2[t] = a > 0.f ? a : 0.f;
  }
  __syncthreads();
  if (t < 2){
    float a = b3[t];
    for (int k=0;k<96;k++) a = fmaf(y2[k], W3[k*2 + t], a);
    z[t] = a;
  }
  __syncthreads();
  if (t == 0){
    float m = fmaxf(z[0], z[1]);
    float l = m + logf(__expf(z[0]-m) + __expf(z[1]-m));
    out[0] = z[0] - l;
    out[1] = z[1] - l;
  }
}

extern "C" void kernel_launch(void* const* d_in, const int* in_sizes, int n_in,
                              void* d_out, int out_size, void* d_ws, size_t ws_size,
                              hipStream_t stream) {
  const float* x_s  = (const float*)d_in[0];
  const float* x_g  = (const float*)d_in[1];
  const float* x_t  = (const float*)d_in[2];
  const float* Wc_s = (const float*)d_in[3];
  const float* bc_s = (const float*)d_in[4];
  const float* Wc_g = (const float*)d_in[5];
  const float* bc_g = (const float*)d_in[6];
  const float* Wc_t = (const float*)d_in[7];
  const float* bc_t = (const float*)d_in[8];
  const float* Wx   = (const float*)d_in[9];
  const float* bx   = (const float*)d_in[10];
  const float* Wgat = (const float*)d_in[11];
  const float* al   = (const float*)d_in[12];
  const float* ar   = (const float*)d_in[13];
  const float* bgat = (const float*)d_in[14];
  const float* W1   = (const float*)d_in[15];
  const float* b1   = (const float*)d_in[16];
  const float* W2   = (const float*)d_in[17];
  const float* b2   = (const float*)d_in[18];
  const float* W3   = (const float*)d_in[19];
  const float* b3   = (const float*)d_in[20];
  const int* src_s  = (const int*)d_in[21];
  const int* dst_s  = (const int*)d_in[22];
  const int* src_g  = (const int*)d_in[23];
  const int* dst_g  = (const int*)d_in[24];
  const int* src_t  = (const int*)d_in[25];
  const int* dst_t  = (const int*)d_in[26];

  float* fb = (float*)d_ws;
  int*   ib = (int*)(fb + 3*GF);
  uchar_t* hb = (uchar_t*)(ib + 3*GI);
  float* sm = (float*)(hb + 3*GH);
  int*   pt = (int*)(sm + 384);              // 3*SCB scan partials
  uint_t* parts_ct = (uint_t*)(pt + 3*SCB + 64);  // 3*BPR*NP packed u16 pairs
  uint_t* parts_no = parts_ct + (size_t)3*BPR*NP;
  float* out = (float*)d_out;

  dim3 b256(256);
  int mmb = (N+63)/64;

  // graph prep: LDS-histogram counting sort (write-localized; RNG=4 passes)
  k_hist      <<<dim3(BPR, RNG, 3),  dim3(1024), 0, stream>>>(parts_ct, parts_no, src_s,dst_s, src_g,dst_g, src_t,dst_t);
  k_scan_local<<<dim3(SCB, 3),       dim3(1024), 0, stream>>>(ib, pt, parts_ct);
  k_scan_part <<<dim3(3),              dim3(64), 0, stream>>>(pt);
  k_scan_apply<<<dim3(SCB, 3),       dim3(1024), 0, stream>>>(fb, ib, pt, parts_no);
  k_slice_off <<<dim3((N+255)/256, 3),     b256, 0, stream>>>(fb, ib, parts_ct);
  k_scatter_r <<<dim3(BPR, RNG, 3),  dim3(1024), 0, stream>>>(fb, ib, src_s,dst_s, src_g,dst_g, src_t,dst_t);

  // initial GCN dense from input x (x never materialized in ws)
  k_mm_gcn0 <<<dim3(mmb, 3), b256, 0, stream>>>(fb, hb, x_s, x_g, x_t,
                                                Wc_s, Wc_g, Wc_t, sm);

  for (int it = 0; it < 2; ++it) {
    k_gcn_agg <<<dim3(3*AGB), b256, 0, stream>>>(fb, hb, ib, bc_s, bc_g, bc_t, it, sm,
                                                 Wgat, al, ar, 1);
    k_exchange<<<dim3(3), dim3(64), 0, stream>>>(fb, sm, Wx, bx, Wgat, al, it);
    k_gat_agg <<<dim3(3*AGB), b256, 0, stream>>>(fb, hb, ib, bgat,
                                                 Wc_s, Wc_g, Wc_t, it+1);
  }

  // final layer readout (no fusion) + MLP head
  k_gcn_agg <<<dim3(3*AGB), b256, 0, stream>>>(fb, hb, ib, bc_s, bc_g, bc_t, 2, sm,
                                               Wgat, al, ar, 0);
  k_mlp     <<<1, 384, 0, stream>>>(sm, W1, b1, W2, b2, W3, b3, out);
}